// Round 1
// baseline (718.366 us; speedup 1.0000x reference)
//
#include <hip/hip_runtime.h>
#include <hip/hip_bf16.h>
#include <stdint.h>

#define T_TOK 4096
#define H_DIM 2048
#define I_DIM 1024
#define NEXP  16
#define SHARED_BASE 10240
#define NROWS 14336

typedef short bf16x8 __attribute__((ext_vector_type(8)));
typedef float f32x4  __attribute__((ext_vector_type(4)));
typedef unsigned short u16;

__device__ __forceinline__ u16 f2b(float f) {
  union { __hip_bfloat16 h; u16 u; } cv;
  cv.h = __float2bfloat16(f);
  return cv.u;
}

__device__ __forceinline__ void gload16(const void* g, void* l) {
  __builtin_amdgcn_global_load_lds((const __attribute__((address_space(1))) void*)g,
                                   (__attribute__((address_space(3))) void*)l, 16, 0, 0);
}

// ---------------- fp32 -> bf16 conversion ----------------
__global__ __launch_bounds__(256) void cvt4_kernel(const float4* __restrict__ src,
                                                   ushort4* __restrict__ dst, int n4) {
  int i = blockIdx.x * 256 + threadIdx.x;
  int stride = gridDim.x * 256;
  for (; i < n4; i += stride) {
    float4 v = src[i];
    ushort4 o;
    o.x = f2b(v.x); o.y = f2b(v.y); o.z = f2b(v.z); o.w = f2b(v.w);
    dst[i] = o;
  }
}

// ---------------- router: fp64 logits, top-2, renormalized weights ----------------
__global__ __launch_bounds__(256) void router_kernel(const float* __restrict__ x,
                                                     const float* __restrict__ gw,
                                                     int* __restrict__ sel,
                                                     float* __restrict__ selw,
                                                     int* __restrict__ counts) {
  int t = blockIdx.x;
  int tid = threadIdx.x;
  const float* xr = x + (size_t)t * H_DIM;
  double p[NEXP];
#pragma unroll
  for (int e = 0; e < NEXP; ++e) p[e] = 0.0;
#pragma unroll
  for (int j = 0; j < 8; ++j) {
    int h = tid * 8 + j;
    double xv = (double)xr[h];
#pragma unroll
    for (int e = 0; e < NEXP; ++e) p[e] += xv * (double)gw[e * H_DIM + h];
  }
#pragma unroll
  for (int e = 0; e < NEXP; ++e) {
#pragma unroll
    for (int off = 32; off > 0; off >>= 1) p[e] += __shfl_down(p[e], off);
  }
  __shared__ double sm[4][NEXP];
  int w = tid >> 6;
  if ((tid & 63) == 0) {
#pragma unroll
    for (int e = 0; e < NEXP; ++e) sm[w][e] = p[e];
  }
  __syncthreads();
  if (tid == 0) {
    double l0 = -1e300, l1 = -1e300;
    int e0 = 0, e1 = 0;
    for (int e = 0; e < NEXP; ++e) {
      double v = sm[0][e] + sm[1][e] + sm[2][e] + sm[3][e];
      if (v > l0) { l1 = l0; e1 = e0; l0 = v; e0 = e; }
      else if (v > l1) { l1 = v; e1 = e; }
    }
    // renormalized top-2 softmax weights: w0 = e^l0/(e^l0+e^l1)
    double w0 = 1.0 / (1.0 + exp(l1 - l0));
    sel[t * 2 + 0] = e0;
    sel[t * 2 + 1] = e1;
    selw[t * 2 + 0] = (float)w0;
    selw[t * 2 + 1] = (float)(1.0 - w0);
    atomicAdd(&counts[e0], 1);
    atomicAdd(&counts[e1], 1);
  }
}

// ---------------- prefix: 128-aligned per-expert row bases ----------------
__global__ void prefix_kernel(const int* __restrict__ counts, int* __restrict__ rowbase) {
  if (threadIdx.x == 0 && blockIdx.x == 0) {
    int acc = 0;
    for (int e = 0; e < NEXP; ++e) {
      rowbase[e] = acc;
      acc += (counts[e] + 127) & ~127;
    }
    rowbase[NEXP] = SHARED_BASE;
  }
}

// ---------------- scatter tokens into packed per-expert row lists ----------------
__global__ __launch_bounds__(256) void scatter_kernel(const int* __restrict__ sel,
                                                      const float* __restrict__ selw,
                                                      const int* __restrict__ rowbase,
                                                      int* __restrict__ cursor,
                                                      int* __restrict__ tok_of_row,
                                                      float* __restrict__ coef_of_row) {
  int idx = blockIdx.x * 256 + threadIdx.x;
  if (idx < T_TOK * 2) {
    int t = idx >> 1;
    int e = sel[idx];
    int slot = atomicAdd(&cursor[e], 1);
    int row = rowbase[e] + slot;
    tok_of_row[row] = t;
    coef_of_row[row] = selw[idx];
  } else if (idx < T_TOK * 3) {
    int t = idx - T_TOK * 2;
    tok_of_row[SHARED_BASE + t] = t;
    coef_of_row[SHARED_BASE + t] = 1.0f;
  }
}

// ---------------- GEMM1: gathered x @ w1e^T + b1e, fused SiLU*mul -> abuf bf16 ----------------
// grid (nt=16, rt=32, e=17), block 256 (4 waves x 32x128 tile)
// block computes 128 rows x 128 acc cols = {g cols nt*64..+64} U {u cols 1024+nt*64..+64}
__global__ __launch_bounds__(256, 2) void gemm1_kernel(
    const u16* __restrict__ x_bf, const u16* __restrict__ W1cat,
    const float* __restrict__ b1, const float* __restrict__ sg_b,
    const int* __restrict__ tok_of_row, const int* __restrict__ counts,
    const int* __restrict__ rowbase, u16* __restrict__ abuf) {
  int nt = blockIdx.x;
  int rt = blockIdx.y;
  int e  = blockIdx.z;
  int n_e = (e < NEXP) ? counts[e] : T_TOK;
  if (rt * 128 >= n_e) return;
  int rbase = (e < NEXP) ? rowbase[e] : SHARED_BASE;
  int n_valid = n_e - rt * 128;
  if (n_valid > 128) n_valid = 128;

  __shared__ short As[2][128 * 64];
  __shared__ short Bs[2][128 * 64];
  __shared__ int Ts[128];

  int tid = threadIdx.x;
  if (tid < 128) Ts[tid] = tok_of_row[rbase + rt * 128 + tid];
  __syncthreads();

  int wbase = tid & 0xC0;  // wave * 64
  const u16* srcA[4];
  const u16* srcB[4];
#pragma unroll
  for (int it = 0; it < 4; ++it) {
    int chunk = it * 256 + tid;
    int row = chunk >> 3, kc = (chunk & 7) * 8;
    int tok = Ts[row]; if (tok < 0) tok = 0;
    srcA[it] = x_bf + (size_t)tok * H_DIM + kc;
    int gcol = (row < 64) ? (nt * 64 + row) : (I_DIM + nt * 64 + (row - 64));
    srcB[it] = W1cat + ((size_t)e * (2 * I_DIM) + gcol) * H_DIM + kc;
  }

  f32x4 acc[2][8];
#pragma unroll
  for (int m = 0; m < 2; ++m)
#pragma unroll
    for (int n = 0; n < 8; ++n) acc[m][n] = (f32x4){0.f, 0.f, 0.f, 0.f};

  int lane = tid & 63;
  int wrow = (tid >> 6) * 32;

  auto stage = [&](int buf, int kt) {
#pragma unroll
    for (int it = 0; it < 4; ++it)
      gload16(srcA[it] + kt * 64, &As[buf][(it * 256 + wbase) * 8]);
#pragma unroll
    for (int it = 0; it < 4; ++it)
      gload16(srcB[it] + kt * 64, &Bs[buf][(it * 256 + wbase) * 8]);
  };
  auto compute = [&](int buf) {
#pragma unroll
    for (int ks = 0; ks < 2; ++ks) {
      bf16x8 a[2], b[8];
#pragma unroll
      for (int m = 0; m < 2; ++m)
        a[m] = *(const bf16x8*)&As[buf][(wrow + 16 * m + (lane & 15)) * 64 + ks * 32 + (lane >> 4) * 8];
#pragma unroll
      for (int n = 0; n < 8; ++n)
        b[n] = *(const bf16x8*)&Bs[buf][(16 * n + (lane & 15)) * 64 + ks * 32 + (lane >> 4) * 8];
#pragma unroll
      for (int m = 0; m < 2; ++m)
#pragma unroll
        for (int n = 0; n < 8; ++n)
          acc[m][n] = __builtin_amdgcn_mfma_f32_16x16x32_bf16(a[m], b[n], acc[m][n], 0, 0, 0);
    }
  };

  stage(0, 0);
  __syncthreads();
  int cur = 0;
  for (int kt = 0; kt < 31; ++kt) {
    stage(cur ^ 1, kt + 1);
    compute(cur);
    __syncthreads();
    cur ^= 1;
  }
  compute(cur);

  const float* bias = (e < NEXP) ? (b1 + (size_t)e * (2 * I_DIM)) : sg_b;
#pragma unroll
  for (int m = 0; m < 2; ++m) {
#pragma unroll
    for (int n = 0; n < 4; ++n) {
      int colg = 16 * n + (lane & 15);
      float bg = bias[nt * 64 + colg];
      float bu = bias[I_DIM + nt * 64 + colg];
#pragma unroll
      for (int reg = 0; reg < 4; ++reg) {
        int r = wrow + 16 * m + (lane >> 4) * 4 + reg;
        if (r < n_valid) {
          float g = acc[m][n][reg] + bg;
          float u = acc[m][n + 4][reg] + bu;
          float s = g / (1.0f + __expf(-g));
          abuf[(size_t)(rbase + rt * 128 + r) * I_DIM + nt * 64 + colg] = f2b(s * u);
        }
      }
    }
  }
}

// ---------------- GEMM2: abuf @ w2e^T * coef -> out (store for shared / atomicAdd for experts) ----------------
template <int ATOMIC>
__global__ __launch_bounds__(256, 2) void gemm2_kernel(
    const u16* __restrict__ abuf, const u16* __restrict__ W2cat,
    const int* __restrict__ tok_of_row, const float* __restrict__ coef_of_row,
    const int* __restrict__ counts, const int* __restrict__ rowbase,
    float* __restrict__ out, int e_force) {
  int nt = blockIdx.x;
  int rt = blockIdx.y;
  int e  = (e_force >= 0) ? e_force : (int)blockIdx.z;
  int n_e = (e < NEXP) ? counts[e] : T_TOK;
  if (rt * 128 >= n_e) return;
  int rbase = (e < NEXP) ? rowbase[e] : SHARED_BASE;
  int n_valid = n_e - rt * 128;
  if (n_valid > 128) n_valid = 128;

  __shared__ short As[2][128 * 64];
  __shared__ short Bs[2][128 * 64];
  __shared__ int Ts[128];
  __shared__ float Cs[128];

  int tid = threadIdx.x;
  if (tid < 128) {
    int row = rbase + rt * 128 + tid;
    Ts[tid] = tok_of_row[row];
    Cs[tid] = coef_of_row[row];
  }

  int wbase = tid & 0xC0;
  const u16* srcA[4];
  const u16* srcB[4];
#pragma unroll
  for (int it = 0; it < 4; ++it) {
    int chunk = it * 256 + tid;
    int row = chunk >> 3, kc = (chunk & 7) * 8;
    srcA[it] = abuf + (size_t)(rbase + rt * 128 + row) * I_DIM + kc;
    srcB[it] = W2cat + ((size_t)e * H_DIM + nt * 128 + row) * I_DIM + kc;
  }

  f32x4 acc[2][8];
#pragma unroll
  for (int m = 0; m < 2; ++m)
#pragma unroll
    for (int n = 0; n < 8; ++n) acc[m][n] = (f32x4){0.f, 0.f, 0.f, 0.f};

  int lane = tid & 63;
  int wrow = (tid >> 6) * 32;

  auto stage = [&](int buf, int kt) {
#pragma unroll
    for (int it = 0; it < 4; ++it)
      gload16(srcA[it] + kt * 64, &As[buf][(it * 256 + wbase) * 8]);
#pragma unroll
    for (int it = 0; it < 4; ++it)
      gload16(srcB[it] + kt * 64, &Bs[buf][(it * 256 + wbase) * 8]);
  };
  auto compute = [&](int buf) {
#pragma unroll
    for (int ks = 0; ks < 2; ++ks) {
      bf16x8 a[2], b[8];
#pragma unroll
      for (int m = 0; m < 2; ++m)
        a[m] = *(const bf16x8*)&As[buf][(wrow + 16 * m + (lane & 15)) * 64 + ks * 32 + (lane >> 4) * 8];
#pragma unroll
      for (int n = 0; n < 8; ++n)
        b[n] = *(const bf16x8*)&Bs[buf][(16 * n + (lane & 15)) * 64 + ks * 32 + (lane >> 4) * 8];
#pragma unroll
      for (int m = 0; m < 2; ++m)
#pragma unroll
        for (int n = 0; n < 8; ++n)
          acc[m][n] = __builtin_amdgcn_mfma_f32_16x16x32_bf16(a[m], b[n], acc[m][n], 0, 0, 0);
    }
  };

  stage(0, 0);
  __syncthreads();
  int cur = 0;
  for (int kt = 0; kt < 15; ++kt) {
    stage(cur ^ 1, kt + 1);
    compute(cur);
    __syncthreads();
    cur ^= 1;
  }
  compute(cur);

#pragma unroll
  for (int m = 0; m < 2; ++m) {
#pragma unroll
    for (int n = 0; n < 8; ++n) {
      int col = nt * 128 + 16 * n + (lane & 15);
#pragma unroll
      for (int reg = 0; reg < 4; ++reg) {
        int r = wrow + 16 * m + (lane >> 4) * 4 + reg;
        if (r < n_valid) {
          int tok = Ts[r];
          float val = acc[m][n][reg] * Cs[r];
          float* p = out + (size_t)tok * H_DIM + col;
          if (ATOMIC) atomicAdd(p, val);
          else *p = val;
        }
      }
    }
  }
}

// ---------------- launch ----------------
extern "C" void kernel_launch(void* const* d_in, const int* in_sizes, int n_in,
                              void* d_out, int out_size, void* d_ws, size_t ws_size,
                              hipStream_t stream) {
  const float* x    = (const float*)d_in[0];
  const float* gate_w = (const float*)d_in[1];
  const float* w1   = (const float*)d_in[2];
  const float* b1   = (const float*)d_in[3];
  const float* w2   = (const float*)d_in[4];
  const float* sg_w = (const float*)d_in[5];
  const float* sg_b = (const float*)d_in[6];
  const float* sd_w = (const float*)d_in[7];
  float* out = (float*)d_out;

  uint8_t* ws = (uint8_t*)d_ws;
  size_t off = 0;
  auto alloc = [&](size_t bytes) -> void* {
    void* p = ws + off;
    off += (bytes + 255) & ~(size_t)255;
    return p;
  };
  u16*  W1cat = (u16*)alloc((size_t)17 * 2048 * 2048 * 2);
  u16*  W2cat = (u16*)alloc((size_t)17 * 2048 * 1024 * 2);
  u16*  x_bf  = (u16*)alloc((size_t)T_TOK * H_DIM * 2);
  u16*  abuf  = (u16*)alloc((size_t)NROWS * I_DIM * 2);
  int*  tok_of_row  = (int*)alloc((size_t)NROWS * 4);
  float* coef_of_row = (float*)alloc((size_t)NROWS * 4);
  int*  sel   = (int*)alloc((size_t)T_TOK * 2 * 4);
  float* selw = (float*)alloc((size_t)T_TOK * 2 * 4);
  int*  counts  = (int*)alloc(256);
  int*  cursor  = (int*)alloc(256);
  int*  rowbase = (int*)alloc(256);
  (void)ws_size; (void)in_sizes; (void)n_in; (void)out_size;

  hipMemsetAsync(counts, 0, 768, stream);                       // counts+cursor+rowbase
  hipMemsetAsync(tok_of_row, 0xFF, (size_t)NROWS * 4, stream);  // -1 = pad row

  auto cvt = [&](const float* s, u16* d, size_t n) {
    int n4 = (int)(n / 4);
    int blocks = (n4 + 255) / 256;
    if (blocks > 2048) blocks = 2048;
    cvt4_kernel<<<dim3(blocks), dim3(256), 0, stream>>>((const float4*)s, (ushort4*)d, n4);
  };
  cvt(w1,   W1cat, (size_t)16 * 2048 * 2048);
  cvt(sg_w, W1cat + (size_t)16 * 2048 * 2048, (size_t)2048 * 2048);
  cvt(w2,   W2cat, (size_t)16 * 2048 * 1024);
  cvt(sd_w, W2cat + (size_t)16 * 2048 * 1024, (size_t)2048 * 1024);
  cvt(x,    x_bf, (size_t)T_TOK * H_DIM);

  router_kernel<<<dim3(T_TOK), dim3(256), 0, stream>>>(x, gate_w, sel, selw, counts);
  prefix_kernel<<<dim3(1), dim3(64), 0, stream>>>(counts, rowbase);
  scatter_kernel<<<dim3(48), dim3(256), 0, stream>>>(sel, selw, rowbase, cursor, tok_of_row, coef_of_row);

  gemm1_kernel<<<dim3(16, 32, 17), dim3(256), 0, stream>>>(
      x_bf, W1cat, b1, sg_b, tok_of_row, counts, rowbase, abuf);

  // shared expert first: plain stores cover every out element, then routed experts atomicAdd
  gemm2_kernel<0><<<dim3(16, 32, 1), dim3(256), 0, stream>>>(
      abuf, W2cat, tok_of_row, coef_of_row, counts, rowbase, out, NEXP);
  gemm2_kernel<1><<<dim3(16, 32, 16), dim3(256), 0, stream>>>(
      abuf, W2cat, tok_of_row, coef_of_row, counts, rowbase, out, -1);
}

// Round 2
// 593.468 us; speedup vs baseline: 1.2105x; 1.2105x over previous
//
#include <hip/hip_runtime.h>
#include <hip/hip_bf16.h>
#include <stdint.h>

#define T_TOK 4096
#define H_DIM 2048
#define I_DIM 1024
#define NEXP  16
#define SHARED_BASE 10240
#define NROWS 14336

typedef short bf16x8 __attribute__((ext_vector_type(8)));
typedef float f32x4  __attribute__((ext_vector_type(4)));
typedef unsigned short u16;

__device__ __forceinline__ u16 f2b(float f) {
  union { __hip_bfloat16 h; u16 u; } cv;
  cv.h = __float2bfloat16(f);
  return cv.u;
}

__device__ __forceinline__ void gload16(const void* g, void* l) {
  __builtin_amdgcn_global_load_lds((const __attribute__((address_space(1))) void*)g,
                                   (__attribute__((address_space(3))) void*)l, 16, 0, 0);
}

// ---------------- fp32 -> bf16 conversion ----------------
__global__ __launch_bounds__(256) void cvt4_kernel(const float4* __restrict__ src,
                                                   ushort4* __restrict__ dst, int n4) {
  int i = blockIdx.x * 256 + threadIdx.x;
  int stride = gridDim.x * 256;
  for (; i < n4; i += stride) {
    float4 v = src[i];
    ushort4 o;
    o.x = f2b(v.x); o.y = f2b(v.y); o.z = f2b(v.z); o.w = f2b(v.w);
    dst[i] = o;
  }
}

// ---------------- router: fp64 logits, top-2, renormalized weights ----------------
__global__ __launch_bounds__(256) void router_kernel(const float* __restrict__ x,
                                                     const float* __restrict__ gw,
                                                     int* __restrict__ sel,
                                                     float* __restrict__ selw,
                                                     int* __restrict__ counts) {
  int t = blockIdx.x;
  int tid = threadIdx.x;
  const float* xr = x + (size_t)t * H_DIM;
  double p[NEXP];
#pragma unroll
  for (int e = 0; e < NEXP; ++e) p[e] = 0.0;
#pragma unroll
  for (int j = 0; j < 8; ++j) {
    int h = tid * 8 + j;
    double xv = (double)xr[h];
#pragma unroll
    for (int e = 0; e < NEXP; ++e) p[e] += xv * (double)gw[e * H_DIM + h];
  }
#pragma unroll
  for (int e = 0; e < NEXP; ++e) {
#pragma unroll
    for (int off = 32; off > 0; off >>= 1) p[e] += __shfl_down(p[e], off);
  }
  __shared__ double sm[4][NEXP];
  int w = tid >> 6;
  if ((tid & 63) == 0) {
#pragma unroll
    for (int e = 0; e < NEXP; ++e) sm[w][e] = p[e];
  }
  __syncthreads();
  if (tid == 0) {
    double l0 = -1e300, l1 = -1e300;
    int e0 = 0, e1 = 0;
    for (int e = 0; e < NEXP; ++e) {
      double v = sm[0][e] + sm[1][e] + sm[2][e] + sm[3][e];
      if (v > l0) { l1 = l0; e1 = e0; l0 = v; e0 = e; }
      else if (v > l1) { l1 = v; e1 = e; }
    }
    double w0 = 1.0 / (1.0 + exp(l1 - l0));
    sel[t * 2 + 0] = e0;
    sel[t * 2 + 1] = e1;
    selw[t * 2 + 0] = (float)w0;
    selw[t * 2 + 1] = (float)(1.0 - w0);
    atomicAdd(&counts[e0], 1);
    atomicAdd(&counts[e1], 1);
  }
}

// ---------------- prefix: 128-aligned per-expert row bases ----------------
__global__ void prefix_kernel(const int* __restrict__ counts, int* __restrict__ rowbase) {
  if (threadIdx.x == 0 && blockIdx.x == 0) {
    int acc = 0;
    for (int e = 0; e < NEXP; ++e) {
      rowbase[e] = acc;
      acc += (counts[e] + 127) & ~127;
    }
    rowbase[NEXP] = SHARED_BASE;
  }
}

// ---------------- scatter tokens into packed per-expert row lists ----------------
__global__ __launch_bounds__(256) void scatter_kernel(const int* __restrict__ sel,
                                                      const float* __restrict__ selw,
                                                      const int* __restrict__ rowbase,
                                                      int* __restrict__ cursor,
                                                      int* __restrict__ tok_of_row,
                                                      float* __restrict__ coef_of_row) {
  int idx = blockIdx.x * 256 + threadIdx.x;
  if (idx < T_TOK * 2) {
    int t = idx >> 1;
    int e = sel[idx];
    int slot = atomicAdd(&cursor[e], 1);
    int row = rowbase[e] + slot;
    tok_of_row[row] = t;
    coef_of_row[row] = selw[idx];
  } else if (idx < T_TOK * 3) {
    int t = idx - T_TOK * 2;
    tok_of_row[SHARED_BASE + t] = t;
    coef_of_row[SHARED_BASE + t] = 1.0f;
  }
}

// ---------------- GEMM1: gathered x @ w1e^T + b1e, fused SiLU*mul -> abuf bf16 ----------------
// grid (nt=16, rt=32, e=17), block 256 (4 waves x 32x128 tile)
// single-buffered LDS (33KB) -> 4 blocks/CU; implicit wave overlap does the pipelining (m114)
__global__ __launch_bounds__(256, 4) void gemm1_kernel(
    const u16* __restrict__ x_bf, const u16* __restrict__ W1cat,
    const float* __restrict__ b1, const float* __restrict__ sg_b,
    const int* __restrict__ tok_of_row, const int* __restrict__ counts,
    const int* __restrict__ rowbase, u16* __restrict__ abuf) {
  int nt = blockIdx.x;
  int rt = blockIdx.y;
  int e  = blockIdx.z;
  int n_e = (e < NEXP) ? counts[e] : T_TOK;
  if (rt * 128 >= n_e) return;
  int rbase = (e < NEXP) ? rowbase[e] : SHARED_BASE;
  int n_valid = n_e - rt * 128;
  if (n_valid > 128) n_valid = 128;

  __shared__ short As[128 * 64];
  __shared__ short Bs[128 * 64];
  __shared__ int Ts[128];

  int tid = threadIdx.x;
  if (tid < 128) Ts[tid] = tok_of_row[rbase + rt * 128 + tid];
  __syncthreads();

  int wbase = tid & 0xC0;  // wave * 64
  const u16* srcA[4];
  const u16* srcB[4];
#pragma unroll
  for (int it = 0; it < 4; ++it) {
    int chunk = it * 256 + tid;
    int row = chunk >> 3, kc = (chunk & 7) * 8;
    int tok = Ts[row]; if (tok < 0) tok = 0;
    srcA[it] = x_bf + (size_t)tok * H_DIM + kc;
    int gcol = (row < 64) ? (nt * 64 + row) : (I_DIM + nt * 64 + (row - 64));
    srcB[it] = W1cat + ((size_t)e * (2 * I_DIM) + gcol) * H_DIM + kc;
  }

  f32x4 acc[2][8];
#pragma unroll
  for (int m = 0; m < 2; ++m)
#pragma unroll
    for (int n = 0; n < 8; ++n) acc[m][n] = (f32x4){0.f, 0.f, 0.f, 0.f};

  int lane = tid & 63;
  int wrow = (tid >> 6) * 32;

  for (int kt = 0; kt < 32; ++kt) {
    if (kt) __syncthreads();  // previous compute done before overwrite
#pragma unroll
    for (int it = 0; it < 4; ++it)
      gload16(srcA[it] + kt * 64, &As[(it * 256 + wbase) * 8]);
#pragma unroll
    for (int it = 0; it < 4; ++it)
      gload16(srcB[it] + kt * 64, &Bs[(it * 256 + wbase) * 8]);
    __syncthreads();  // vmcnt(0) drain: staged data visible
#pragma unroll
    for (int ks = 0; ks < 2; ++ks) {
      bf16x8 a[2], b[8];
#pragma unroll
      for (int m = 0; m < 2; ++m)
        a[m] = *(const bf16x8*)&As[(wrow + 16 * m + (lane & 15)) * 64 + ks * 32 + (lane >> 4) * 8];
#pragma unroll
      for (int n = 0; n < 8; ++n)
        b[n] = *(const bf16x8*)&Bs[(16 * n + (lane & 15)) * 64 + ks * 32 + (lane >> 4) * 8];
#pragma unroll
      for (int m = 0; m < 2; ++m)
#pragma unroll
        for (int n = 0; n < 8; ++n)
          acc[m][n] = __builtin_amdgcn_mfma_f32_16x16x32_bf16(a[m], b[n], acc[m][n], 0, 0, 0);
    }
  }

  const float* bias = (e < NEXP) ? (b1 + (size_t)e * (2 * I_DIM)) : sg_b;
#pragma unroll
  for (int m = 0; m < 2; ++m) {
#pragma unroll
    for (int n = 0; n < 4; ++n) {
      int colg = 16 * n + (lane & 15);
      float bg = bias[nt * 64 + colg];
      float bu = bias[I_DIM + nt * 64 + colg];
#pragma unroll
      for (int reg = 0; reg < 4; ++reg) {
        int r = wrow + 16 * m + (lane >> 4) * 4 + reg;
        if (r < n_valid) {
          float g = acc[m][n][reg] + bg;
          float u = acc[m][n + 4][reg] + bu;
          float s = g / (1.0f + __expf(-g));
          abuf[(size_t)(rbase + rt * 128 + r) * I_DIM + nt * 64 + colg] = f2b(s * u);
        }
      }
    }
  }
}

// ---------------- GEMM2: abuf @ w2e^T * coef -> out (store for shared / atomicAdd for experts) ----------------
template <int ATOMIC>
__global__ __launch_bounds__(256, 4) void gemm2_kernel(
    const u16* __restrict__ abuf, const u16* __restrict__ W2cat,
    const int* __restrict__ tok_of_row, const float* __restrict__ coef_of_row,
    const int* __restrict__ counts, const int* __restrict__ rowbase,
    float* __restrict__ out, int e_force) {
  int nt = blockIdx.x;
  int rt = blockIdx.y;
  int e  = (e_force >= 0) ? e_force : (int)blockIdx.z;
  int n_e = (e < NEXP) ? counts[e] : T_TOK;
  if (rt * 128 >= n_e) return;
  int rbase = (e < NEXP) ? rowbase[e] : SHARED_BASE;
  int n_valid = n_e - rt * 128;
  if (n_valid > 128) n_valid = 128;

  __shared__ short As[128 * 64];
  __shared__ short Bs[128 * 64];
  __shared__ int Ts[128];
  __shared__ float Cs[128];

  int tid = threadIdx.x;
  if (tid < 128) {
    int row = rbase + rt * 128 + tid;
    Ts[tid] = tok_of_row[row];
    Cs[tid] = coef_of_row[row];
  }
  __syncthreads();

  int wbase = tid & 0xC0;
  const u16* srcA[4];
  const u16* srcB[4];
#pragma unroll
  for (int it = 0; it < 4; ++it) {
    int chunk = it * 256 + tid;
    int row = chunk >> 3, kc = (chunk & 7) * 8;
    srcA[it] = abuf + (size_t)(rbase + rt * 128 + row) * I_DIM + kc;
    srcB[it] = W2cat + ((size_t)e * H_DIM + nt * 128 + row) * I_DIM + kc;
  }

  f32x4 acc[2][8];
#pragma unroll
  for (int m = 0; m < 2; ++m)
#pragma unroll
    for (int n = 0; n < 8; ++n) acc[m][n] = (f32x4){0.f, 0.f, 0.f, 0.f};

  int lane = tid & 63;
  int wrow = (tid >> 6) * 32;

  for (int kt = 0; kt < 16; ++kt) {
    if (kt) __syncthreads();
#pragma unroll
    for (int it = 0; it < 4; ++it)
      gload16(srcA[it] + kt * 64, &As[(it * 256 + wbase) * 8]);
#pragma unroll
    for (int it = 0; it < 4; ++it)
      gload16(srcB[it] + kt * 64, &Bs[(it * 256 + wbase) * 8]);
    __syncthreads();
#pragma unroll
    for (int ks = 0; ks < 2; ++ks) {
      bf16x8 a[2], b[8];
#pragma unroll
      for (int m = 0; m < 2; ++m)
        a[m] = *(const bf16x8*)&As[(wrow + 16 * m + (lane & 15)) * 64 + ks * 32 + (lane >> 4) * 8];
#pragma unroll
      for (int n = 0; n < 8; ++n)
        b[n] = *(const bf16x8*)&Bs[(16 * n + (lane & 15)) * 64 + ks * 32 + (lane >> 4) * 8];
#pragma unroll
      for (int m = 0; m < 2; ++m)
#pragma unroll
        for (int n = 0; n < 8; ++n)
          acc[m][n] = __builtin_amdgcn_mfma_f32_16x16x32_bf16(a[m], b[n], acc[m][n], 0, 0, 0);
    }
  }

#pragma unroll
  for (int m = 0; m < 2; ++m) {
#pragma unroll
    for (int n = 0; n < 8; ++n) {
      int col = nt * 128 + 16 * n + (lane & 15);
#pragma unroll
      for (int reg = 0; reg < 4; ++reg) {
        int r = wrow + 16 * m + (lane >> 4) * 4 + reg;
        if (r < n_valid) {
          int tok = Ts[r];
          float val = acc[m][n][reg] * Cs[r];
          float* p = out + (size_t)tok * H_DIM + col;
          if (ATOMIC) atomicAdd(p, val);
          else *p = val;
        }
      }
    }
  }
}

// ---------------- launch ----------------
extern "C" void kernel_launch(void* const* d_in, const int* in_sizes, int n_in,
                              void* d_out, int out_size, void* d_ws, size_t ws_size,
                              hipStream_t stream) {
  const float* x    = (const float*)d_in[0];
  const float* gate_w = (const float*)d_in[1];
  const float* w1   = (const float*)d_in[2];
  const float* b1   = (const float*)d_in[3];
  const float* w2   = (const float*)d_in[4];
  const float* sg_w = (const float*)d_in[5];
  const float* sg_b = (const float*)d_in[6];
  const float* sd_w = (const float*)d_in[7];
  float* out = (float*)d_out;

  uint8_t* ws = (uint8_t*)d_ws;
  size_t off = 0;
  auto alloc = [&](size_t bytes) -> void* {
    void* p = ws + off;
    off += (bytes + 255) & ~(size_t)255;
    return p;
  };
  u16*  W1cat = (u16*)alloc((size_t)17 * 2048 * 2048 * 2);
  u16*  W2cat = (u16*)alloc((size_t)17 * 2048 * 1024 * 2);
  u16*  x_bf  = (u16*)alloc((size_t)T_TOK * H_DIM * 2);
  u16*  abuf  = (u16*)alloc((size_t)NROWS * I_DIM * 2);
  int*  tok_of_row  = (int*)alloc((size_t)NROWS * 4);
  float* coef_of_row = (float*)alloc((size_t)NROWS * 4);
  int*  sel   = (int*)alloc((size_t)T_TOK * 2 * 4);
  float* selw = (float*)alloc((size_t)T_TOK * 2 * 4);
  int*  counts  = (int*)alloc(256);
  int*  cursor  = (int*)alloc(256);
  int*  rowbase = (int*)alloc(256);
  (void)ws_size; (void)in_sizes; (void)n_in; (void)out_size;

  hipMemsetAsync(counts, 0, 768, stream);                       // counts+cursor+rowbase
  hipMemsetAsync(tok_of_row, 0xFF, (size_t)NROWS * 4, stream);  // -1 = pad row

  auto cvt = [&](const float* s, u16* d, size_t n) {
    int n4 = (int)(n / 4);
    int blocks = (n4 + 255) / 256;
    if (blocks > 2048) blocks = 2048;
    cvt4_kernel<<<dim3(blocks), dim3(256), 0, stream>>>((const float4*)s, (ushort4*)d, n4);
  };
  cvt(w1,   W1cat, (size_t)16 * 2048 * 2048);
  cvt(sg_w, W1cat + (size_t)16 * 2048 * 2048, (size_t)2048 * 2048);
  cvt(w2,   W2cat, (size_t)16 * 2048 * 1024);
  cvt(sd_w, W2cat + (size_t)16 * 2048 * 1024, (size_t)2048 * 1024);
  cvt(x,    x_bf, (size_t)T_TOK * H_DIM);

  router_kernel<<<dim3(T_TOK), dim3(256), 0, stream>>>(x, gate_w, sel, selw, counts);
  prefix_kernel<<<dim3(1), dim3(64), 0, stream>>>(counts, rowbase);
  scatter_kernel<<<dim3(48), dim3(256), 0, stream>>>(sel, selw, rowbase, cursor, tok_of_row, coef_of_row);

  gemm1_kernel<<<dim3(16, 32, 17), dim3(256), 0, stream>>>(
      x_bf, W1cat, b1, sg_b, tok_of_row, counts, rowbase, abuf);

  // shared expert first: plain stores cover every out element, then routed experts atomicAdd
  gemm2_kernel<0><<<dim3(16, 32, 1), dim3(256), 0, stream>>>(
      abuf, W2cat, tok_of_row, coef_of_row, counts, rowbase, out, NEXP);
  gemm2_kernel<1><<<dim3(16, 32, 16), dim3(256), 0, stream>>>(
      abuf, W2cat, tok_of_row, coef_of_row, counts, rowbase, out, -1);
}

// Round 3
// 574.017 us; speedup vs baseline: 1.2515x; 1.0339x over previous
//
#include <hip/hip_runtime.h>
#include <hip/hip_bf16.h>
#include <stdint.h>

#define T_TOK 4096
#define H_DIM 2048
#define I_DIM 1024
#define NEXP  16
#define SHARED_BASE 10240
#define NROWS 14336

typedef short bf16x8 __attribute__((ext_vector_type(8)));
typedef float f32x4  __attribute__((ext_vector_type(4)));
typedef unsigned short u16;

__device__ __forceinline__ u16 f2b(float f) {
  union { __hip_bfloat16 h; u16 u; } cv;
  cv.h = __float2bfloat16(f);
  return cv.u;
}

__device__ __forceinline__ void gload16(const void* g, void* l) {
  __builtin_amdgcn_global_load_lds((const __attribute__((address_space(1))) void*)g,
                                   (__attribute__((address_space(3))) void*)l, 16, 0, 0);
}

// pack 8 fp32 (two float4) -> bf16x8
__device__ __forceinline__ bf16x8 pack8(const float4 a, const float4 b) {
  bf16x8 o;
  o[0] = (short)f2b(a.x); o[1] = (short)f2b(a.y);
  o[2] = (short)f2b(a.z); o[3] = (short)f2b(a.w);
  o[4] = (short)f2b(b.x); o[5] = (short)f2b(b.y);
  o[6] = (short)f2b(b.z); o[7] = (short)f2b(b.w);
  return o;
}

// ---------------- fp32 -> bf16 conversion (x only) ----------------
__global__ __launch_bounds__(256) void cvt4_kernel(const float4* __restrict__ src,
                                                   ushort4* __restrict__ dst, int n4) {
  int i = blockIdx.x * 256 + threadIdx.x;
  int stride = gridDim.x * 256;
  for (; i < n4; i += stride) {
    float4 v = src[i];
    ushort4 o;
    o.x = f2b(v.x); o.y = f2b(v.y); o.z = f2b(v.z); o.w = f2b(v.w);
    dst[i] = o;
  }
}

// ---------------- router: fp64 logits, top-2, renormalized weights ----------------
__global__ __launch_bounds__(256) void router_kernel(const float* __restrict__ x,
                                                     const float* __restrict__ gw,
                                                     int* __restrict__ sel,
                                                     float* __restrict__ selw,
                                                     int* __restrict__ counts) {
  int t = blockIdx.x;
  int tid = threadIdx.x;
  const float* xr = x + (size_t)t * H_DIM;
  double p[NEXP];
#pragma unroll
  for (int e = 0; e < NEXP; ++e) p[e] = 0.0;
#pragma unroll
  for (int j = 0; j < 8; ++j) {
    int h = tid * 8 + j;
    double xv = (double)xr[h];
#pragma unroll
    for (int e = 0; e < NEXP; ++e) p[e] += xv * (double)gw[e * H_DIM + h];
  }
#pragma unroll
  for (int e = 0; e < NEXP; ++e) {
#pragma unroll
    for (int off = 32; off > 0; off >>= 1) p[e] += __shfl_down(p[e], off);
  }
  __shared__ double sm[4][NEXP];
  int w = tid >> 6;
  if ((tid & 63) == 0) {
#pragma unroll
    for (int e = 0; e < NEXP; ++e) sm[w][e] = p[e];
  }
  __syncthreads();
  if (tid == 0) {
    double l0 = -1e300, l1 = -1e300;
    int e0 = 0, e1 = 0;
    for (int e = 0; e < NEXP; ++e) {
      double v = sm[0][e] + sm[1][e] + sm[2][e] + sm[3][e];
      if (v > l0) { l1 = l0; e1 = e0; l0 = v; e0 = e; }
      else if (v > l1) { l1 = v; e1 = e; }
    }
    double w0 = 1.0 / (1.0 + exp(l1 - l0));
    sel[t * 2 + 0] = e0;
    sel[t * 2 + 1] = e1;
    selw[t * 2 + 0] = (float)w0;
    selw[t * 2 + 1] = (float)(1.0 - w0);
    atomicAdd(&counts[e0], 1);
    atomicAdd(&counts[e1], 1);
  }
}

// ---------------- prefix: 128-aligned per-expert row bases ----------------
__global__ void prefix_kernel(const int* __restrict__ counts, int* __restrict__ rowbase) {
  if (threadIdx.x == 0 && blockIdx.x == 0) {
    int acc = 0;
    for (int e = 0; e < NEXP; ++e) {
      rowbase[e] = acc;
      acc += (counts[e] + 127) & ~127;
    }
    rowbase[NEXP] = SHARED_BASE;
  }
}

// ---------------- scatter tokens into packed per-expert row lists ----------------
__global__ __launch_bounds__(256) void scatter_kernel(const int* __restrict__ sel,
                                                      const float* __restrict__ selw,
                                                      const int* __restrict__ rowbase,
                                                      int* __restrict__ cursor,
                                                      int* __restrict__ tok_of_row,
                                                      float* __restrict__ coef_of_row) {
  int idx = blockIdx.x * 256 + threadIdx.x;
  if (idx < T_TOK * 2) {
    int t = idx >> 1;
    int e = sel[idx];
    int slot = atomicAdd(&cursor[e], 1);
    int row = rowbase[e] + slot;
    tok_of_row[row] = t;
    coef_of_row[row] = selw[idx];
  } else if (idx < T_TOK * 3) {
    int t = idx - T_TOK * 2;
    tok_of_row[SHARED_BASE + t] = t;
    coef_of_row[SHARED_BASE + t] = 1.0f;
  }
}

// ---------------- GEMM1: gathered x @ w1e^T + b1e, fused SiLU*mul -> abuf bf16 ----------------
// A (x rows, bf16) via global_load_lds; B (W1 fp32) reg-staged with inline cvt (kills cvt pass).
// T14 split: B fp32 loads for step kt+1 issued after the drain barrier -> fly during compute(kt).
__global__ __launch_bounds__(256, 4) void gemm1_kernel(
    const u16* __restrict__ x_bf, const float* __restrict__ w1,
    const float* __restrict__ sg_w,
    const float* __restrict__ b1, const float* __restrict__ sg_b,
    const int* __restrict__ tok_of_row, const int* __restrict__ counts,
    const int* __restrict__ rowbase, u16* __restrict__ abuf) {
  int nt = blockIdx.x;
  int rt = blockIdx.y;
  int e  = blockIdx.z;
  int n_e = (e < NEXP) ? counts[e] : T_TOK;
  if (rt * 128 >= n_e) return;
  int rbase = (e < NEXP) ? rowbase[e] : SHARED_BASE;
  int n_valid = n_e - rt * 128;
  if (n_valid > 128) n_valid = 128;

  __shared__ short As[128 * 64];
  __shared__ short Bs[128 * 64];
  __shared__ int Ts[128];

  int tid = threadIdx.x;
  if (tid < 128) Ts[tid] = tok_of_row[rbase + rt * 128 + tid];
  __syncthreads();

  int wbase = tid & 0xC0;  // wave * 64
  const u16* srcA[4];
#pragma unroll
  for (int it = 0; it < 4; ++it) {
    int chunk = it * 256 + tid;
    int row = chunk >> 3, kc = (chunk & 7) * 8;
    int tok = Ts[row]; if (tok < 0) tok = 0;
    srcA[it] = x_bf + (size_t)tok * H_DIM + kc;
  }
  // B: W1 expert slice (fp32). chunk c = p*256+tid -> row=c>>3, kc=(c&7)*8;
  // ds_write byte addr = c*16 (contiguous per wave -> conflict-free).
  const float* Wexp = (e < NEXP) ? (w1 + (size_t)e * (2 * I_DIM) * H_DIM) : sg_w;
  const float* srcBf[4];
  short* dstB[4];
#pragma unroll
  for (int p = 0; p < 4; ++p) {
    int chunk = p * 256 + tid;
    int row = chunk >> 3, kc = (chunk & 7) * 8;
    int gcol = (row < 64) ? (nt * 64 + row) : (I_DIM + nt * 64 + (row - 64));
    srcBf[p] = Wexp + (size_t)gcol * H_DIM + kc;
    dstB[p] = &Bs[row * 64 + kc];
  }

  f32x4 acc[2][8];
#pragma unroll
  for (int m = 0; m < 2; ++m)
#pragma unroll
    for (int n = 0; n < 8; ++n) acc[m][n] = (f32x4){0.f, 0.f, 0.f, 0.f};

  int lane = tid & 63;
  int wrow = (tid >> 6) * 32;

  float4 breg[8];
#pragma unroll
  for (int p = 0; p < 4; ++p) {
    const float4* q = (const float4*)srcBf[p];
    breg[2 * p] = q[0]; breg[2 * p + 1] = q[1];
  }

  for (int kt = 0; kt < 32; ++kt) {
    if (kt) __syncthreads();  // prev compute done + B regs(kt) landed
#pragma unroll
    for (int it = 0; it < 4; ++it)
      gload16(srcA[it] + kt * 64, &As[(it * 256 + wbase) * 8]);
#pragma unroll
    for (int p = 0; p < 4; ++p)
      *(bf16x8*)dstB[p] = pack8(breg[2 * p], breg[2 * p + 1]);
    __syncthreads();  // drain A gload_lds + B ds_writes
    if (kt + 1 < 32) {
#pragma unroll
      for (int p = 0; p < 4; ++p) {
        const float4* q = (const float4*)(srcBf[p] + (kt + 1) * 64);
        breg[2 * p] = q[0]; breg[2 * p + 1] = q[1];
      }
    }
#pragma unroll
    for (int ks = 0; ks < 2; ++ks) {
      bf16x8 a[2], b[8];
#pragma unroll
      for (int m = 0; m < 2; ++m)
        a[m] = *(const bf16x8*)&As[(wrow + 16 * m + (lane & 15)) * 64 + ks * 32 + (lane >> 4) * 8];
#pragma unroll
      for (int n = 0; n < 8; ++n)
        b[n] = *(const bf16x8*)&Bs[(16 * n + (lane & 15)) * 64 + ks * 32 + (lane >> 4) * 8];
#pragma unroll
      for (int m = 0; m < 2; ++m)
#pragma unroll
        for (int n = 0; n < 8; ++n)
          acc[m][n] = __builtin_amdgcn_mfma_f32_16x16x32_bf16(a[m], b[n], acc[m][n], 0, 0, 0);
    }
  }

  const float* bias = (e < NEXP) ? (b1 + (size_t)e * (2 * I_DIM)) : sg_b;
#pragma unroll
  for (int m = 0; m < 2; ++m) {
#pragma unroll
    for (int n = 0; n < 4; ++n) {
      int colg = 16 * n + (lane & 15);
      float bg = bias[nt * 64 + colg];
      float bu = bias[I_DIM + nt * 64 + colg];
#pragma unroll
      for (int reg = 0; reg < 4; ++reg) {
        int r = wrow + 16 * m + (lane >> 4) * 4 + reg;
        if (r < n_valid) {
          float g = acc[m][n][reg] + bg;
          float u = acc[m][n + 4][reg] + bu;
          float s = g / (1.0f + __expf(-g));
          abuf[(size_t)(rbase + rt * 128 + r) * I_DIM + nt * 64 + colg] = f2b(s * u);
        }
      }
    }
  }
}

// ---------------- GEMM2: abuf @ w2e^T * coef -> out ----------------
// A (abuf bf16) via global_load_lds; B (W2 fp32) reg-staged with inline cvt.
template <int ATOMIC>
__global__ __launch_bounds__(256, 4) void gemm2_kernel(
    const u16* __restrict__ abuf, const float* __restrict__ w2,
    const float* __restrict__ sd_w,
    const int* __restrict__ tok_of_row, const float* __restrict__ coef_of_row,
    const int* __restrict__ counts, const int* __restrict__ rowbase,
    float* __restrict__ out, int e_force) {
  int nt = blockIdx.x;
  int rt = blockIdx.y;
  int e  = (e_force >= 0) ? e_force : (int)blockIdx.z;
  int n_e = (e < NEXP) ? counts[e] : T_TOK;
  if (rt * 128 >= n_e) return;
  int rbase = (e < NEXP) ? rowbase[e] : SHARED_BASE;
  int n_valid = n_e - rt * 128;
  if (n_valid > 128) n_valid = 128;

  __shared__ short As[128 * 64];
  __shared__ short Bs[128 * 64];
  __shared__ int Ts[128];
  __shared__ float Cs[128];

  int tid = threadIdx.x;
  if (tid < 128) {
    int row = rbase + rt * 128 + tid;
    Ts[tid] = tok_of_row[row];
    Cs[tid] = coef_of_row[row];
  }
  __syncthreads();

  int wbase = tid & 0xC0;
  const u16* srcA[4];
#pragma unroll
  for (int it = 0; it < 4; ++it) {
    int chunk = it * 256 + tid;
    int row = chunk >> 3, kc = (chunk & 7) * 8;
    srcA[it] = abuf + (size_t)(rbase + rt * 128 + row) * I_DIM + kc;
  }
  const float* Wexp = (e < NEXP) ? (w2 + (size_t)e * H_DIM * I_DIM) : sd_w;
  const float* srcBf[4];
  short* dstB[4];
#pragma unroll
  for (int p = 0; p < 4; ++p) {
    int chunk = p * 256 + tid;
    int row = chunk >> 3, kc = (chunk & 7) * 8;
    srcBf[p] = Wexp + (size_t)(nt * 128 + row) * I_DIM + kc;
    dstB[p] = &Bs[row * 64 + kc];
  }

  f32x4 acc[2][8];
#pragma unroll
  for (int m = 0; m < 2; ++m)
#pragma unroll
    for (int n = 0; n < 8; ++n) acc[m][n] = (f32x4){0.f, 0.f, 0.f, 0.f};

  int lane = tid & 63;
  int wrow = (tid >> 6) * 32;

  float4 breg[8];
#pragma unroll
  for (int p = 0; p < 4; ++p) {
    const float4* q = (const float4*)srcBf[p];
    breg[2 * p] = q[0]; breg[2 * p + 1] = q[1];
  }

  for (int kt = 0; kt < 16; ++kt) {
    if (kt) __syncthreads();
#pragma unroll
    for (int it = 0; it < 4; ++it)
      gload16(srcA[it] + kt * 64, &As[(it * 256 + wbase) * 8]);
#pragma unroll
    for (int p = 0; p < 4; ++p)
      *(bf16x8*)dstB[p] = pack8(breg[2 * p], breg[2 * p + 1]);
    __syncthreads();
    if (kt + 1 < 16) {
#pragma unroll
      for (int p = 0; p < 4; ++p) {
        const float4* q = (const float4*)(srcBf[p] + (kt + 1) * 64);
        breg[2 * p] = q[0]; breg[2 * p + 1] = q[1];
      }
    }
#pragma unroll
    for (int ks = 0; ks < 2; ++ks) {
      bf16x8 a[2], b[8];
#pragma unroll
      for (int m = 0; m < 2; ++m)
        a[m] = *(const bf16x8*)&As[(wrow + 16 * m + (lane & 15)) * 64 + ks * 32 + (lane >> 4) * 8];
#pragma unroll
      for (int n = 0; n < 8; ++n)
        b[n] = *(const bf16x8*)&Bs[(16 * n + (lane & 15)) * 64 + ks * 32 + (lane >> 4) * 8];
#pragma unroll
      for (int m = 0; m < 2; ++m)
#pragma unroll
        for (int n = 0; n < 8; ++n)
          acc[m][n] = __builtin_amdgcn_mfma_f32_16x16x32_bf16(a[m], b[n], acc[m][n], 0, 0, 0);
    }
  }

#pragma unroll
  for (int m = 0; m < 2; ++m) {
#pragma unroll
    for (int n = 0; n < 8; ++n) {
      int col = nt * 128 + 16 * n + (lane & 15);
#pragma unroll
      for (int reg = 0; reg < 4; ++reg) {
        int r = wrow + 16 * m + (lane >> 4) * 4 + reg;
        if (r < n_valid) {
          int tok = Ts[r];
          float val = acc[m][n][reg] * Cs[r];
          float* p = out + (size_t)tok * H_DIM + col;
          if (ATOMIC) atomicAdd(p, val);
          else *p = val;
        }
      }
    }
  }
}

// ---------------- launch ----------------
extern "C" void kernel_launch(void* const* d_in, const int* in_sizes, int n_in,
                              void* d_out, int out_size, void* d_ws, size_t ws_size,
                              hipStream_t stream) {
  const float* x    = (const float*)d_in[0];
  const float* gate_w = (const float*)d_in[1];
  const float* w1   = (const float*)d_in[2];
  const float* b1   = (const float*)d_in[3];
  const float* w2   = (const float*)d_in[4];
  const float* sg_w = (const float*)d_in[5];
  const float* sg_b = (const float*)d_in[6];
  const float* sd_w = (const float*)d_in[7];
  float* out = (float*)d_out;

  uint8_t* ws = (uint8_t*)d_ws;
  size_t off = 0;
  auto alloc = [&](size_t bytes) -> void* {
    void* p = ws + off;
    off += (bytes + 255) & ~(size_t)255;
    return p;
  };
  u16*  x_bf  = (u16*)alloc((size_t)T_TOK * H_DIM * 2);
  u16*  abuf  = (u16*)alloc((size_t)NROWS * I_DIM * 2);
  int*  tok_of_row  = (int*)alloc((size_t)NROWS * 4);
  float* coef_of_row = (float*)alloc((size_t)NROWS * 4);
  int*  sel   = (int*)alloc((size_t)T_TOK * 2 * 4);
  float* selw = (float*)alloc((size_t)T_TOK * 2 * 4);
  int*  counts  = (int*)alloc(256);
  int*  cursor  = (int*)alloc(256);
  int*  rowbase = (int*)alloc(256);
  (void)ws_size; (void)in_sizes; (void)n_in; (void)out_size;

  hipMemsetAsync(counts, 0, 768, stream);                       // counts+cursor+rowbase
  hipMemsetAsync(tok_of_row, 0xFF, (size_t)NROWS * 4, stream);  // -1 = pad row

  {
    int n4 = (int)((size_t)T_TOK * H_DIM / 4);
    cvt4_kernel<<<dim3(2048), dim3(256), 0, stream>>>((const float4*)x, (ushort4*)x_bf, n4);
  }

  router_kernel<<<dim3(T_TOK), dim3(256), 0, stream>>>(x, gate_w, sel, selw, counts);
  prefix_kernel<<<dim3(1), dim3(64), 0, stream>>>(counts, rowbase);
  scatter_kernel<<<dim3(48), dim3(256), 0, stream>>>(sel, selw, rowbase, cursor, tok_of_row, coef_of_row);

  gemm1_kernel<<<dim3(16, 32, 17), dim3(256), 0, stream>>>(
      x_bf, w1, sg_w, b1, sg_b, tok_of_row, counts, rowbase, abuf);

  // shared expert first: plain stores cover every out element, then routed experts atomicAdd
  gemm2_kernel<0><<<dim3(16, 32, 1), dim3(256), 0, stream>>>(
      abuf, w2, sd_w, tok_of_row, coef_of_row, counts, rowbase, out, NEXP);
  gemm2_kernel<1><<<dim3(16, 32, 16), dim3(256), 0, stream>>>(
      abuf, w2, sd_w, tok_of_row, coef_of_row, counts, rowbase, out, -1);
}